// Round 9
// baseline (156.849 us; speedup 1.0000x reference)
//
#include <hip/hip_runtime.h>
#include <hip/hip_bf16.h>
#include <stdint.h>

#define HWN 50176   // 224*224
#define NM  1000
#define FD  128
#define NSPLIT 49   // 1024-wide k-chunks
#define KSTEPS 32
#define NSCAN 20
#define NPB 50      // 1000 / 20

typedef __attribute__((ext_vector_type(8))) short short8;
typedef __attribute__((ext_vector_type(4))) float f32x4;

__device__ __forceinline__ unsigned short f2bf(float x) {
    union { float f; unsigned u; } v; v.f = x;
    unsigned r = v.u + 0x7FFFu + ((v.u >> 16) & 1u);
    return (unsigned short)(r >> 16);
}

#define AS1(p) ((const __attribute__((address_space(1))) unsigned int*)(p))
#define AS3(p) ((__attribute__((address_space(3))) unsigned int*)(p))

// Stage 1: A[hw,f] = sum_c img*W, packed bf16 k-tiles (GEMM B operand).
// Tile kt (8192B): 16B chunk (f, j) at slot (f*4+j)^((f>>1)&3).
__global__ __launch_bounds__(256) void k_encode(const float* __restrict__ img,
                                                const float* __restrict__ Wt,
                                                unsigned short* __restrict__ Bpack,
                                                float* __restrict__ rep0part)
{
    const int t = threadIdx.x;
    const int f = t & 127;
    const int kt = blockIdx.x * 2 + (t >> 7);
    const int hw0 = kt * 32;
    float vals[32];
    float rsum = 0.f;
#pragma unroll
    for (int e = 0; e < 32; ++e) {
        const int hw = hw0 + e;
        float a = img[hw] * __builtin_nontemporal_load(Wt + (size_t)hw * FD + f);
        a = fmaf(img[HWN + hw],     __builtin_nontemporal_load(Wt + (size_t)(HWN + hw) * FD + f), a);
        a = fmaf(img[2 * HWN + hw], __builtin_nontemporal_load(Wt + (size_t)(2 * HWN + hw) * FD + f), a);
        vals[e] = a;
        rsum += a;
    }
    char* tile = (char*)Bpack + (size_t)kt * 8192;
#pragma unroll
    for (int j = 0; j < 4; ++j) {
        short8 pk;
#pragma unroll
        for (int e = 0; e < 8; ++e) pk[e] = (short)f2bf(vals[j * 8 + e]);
        const int slot = (f * 4 + j) ^ ((f >> 1) & 3);
        *reinterpret_cast<short8*>(tile + (slot << 4)) = pk;
    }
    __shared__ float red[256];
    red[t] = rsum;
    __syncthreads();
    if (t < 128) rep0part[(size_t)blockIdx.x * 128 + f] = red[t] + red[t + 128];
}

// Stage 2: rep0[f] = sum of 784 partials
__global__ __launch_bounds__(256) void k_rep0red(const float* __restrict__ rep0part,
                                                 float* __restrict__ rep0)
{
    const int f = blockIdx.x;
    float s = 0.f;
    for (int b = threadIdx.x; b < 784; b += 256) s += rep0part[(size_t)b * 128 + f];
    __shared__ float red[256];
    red[threadIdx.x] = s;
    __syncthreads();
    for (int o = 128; o > 0; o >>= 1) {
        if (threadIdx.x < o) red[threadIdx.x] += red[threadIdx.x + o];
        __syncthreads();
    }
    if (threadIdx.x == 0) rep0[f] = red[0];
}

// Stage 3: phase-split GEMM. Block = 32 rows x 1024 k, grid 32x49=1568.
// PHASE 1: wave-contiguous A bursts (each load instr = 1KB of ONE mask row,
// the pattern colsums/fill stream at ~7 TB/s), cvt bf16, swizzled A-LDS.
// PHASE 2: pure-LDS A frags + Bpack gll double-buffer, counted vmcnt.
// 80KB LDS -> 2 blocks/CU: one block's phase-2 overlaps the other's phase-1.
__global__ __launch_bounds__(256, 2) void k_gemm(const float* __restrict__ masks,
                                                 const unsigned short* __restrict__ Bpack,
                                                 float* __restrict__ partial)
{
    __shared__ __align__(16) char Alds[65536];     // 32 rows x 2KB bf16, chunk^=(row&7)
    __shared__ __align__(16) char Blds[2][8192];

    const int t = threadIdx.x;
    const int w = t >> 6, l = t & 63;
    const int lrow = l & 15, kg = l >> 4;

    // XCD grouping: 1568 = 8*196; XCD x -> contiguous swz range, split-major.
    const int bid = blockIdx.x;
    const int swz = (bid & 7) * 196 + (bid >> 3);
    const int split = swz >> 5, mtile = swz & 31;
    const int n0 = mtile * 32;

    // ================= PHASE 1: stage A (32 rows x 4KB) =================
    {
        const int rbase = w * 8;
#pragma unroll
        for (int i = 0; i < 8; ++i) {
            const int row = rbase + i;
            int grow = n0 + row; if (grow >= NM) grow = NM - 1;   // dup rows never read back
            const float* src = masks + (size_t)grow * HWN + split * 1024 + l * 4;
            f32x4 v0 = *reinterpret_cast<const f32x4*>(src);
            f32x4 v1 = *reinterpret_cast<const f32x4*>(src + 256);
            f32x4 v2 = *reinterpret_cast<const f32x4*>(src + 512);
            f32x4 v3 = *reinterpret_cast<const f32x4*>(src + 768);
            char* rb = Alds + row * 2048 + (l & 1) * 8;
            const int cb = (l >> 1);
            union { __hip_bfloat162 h[2]; uint2 u; } p0, p1, p2, p3;
            p0.h[0] = __float22bfloat162_rn(float2{v0[0], v0[1]});
            p0.h[1] = __float22bfloat162_rn(float2{v0[2], v0[3]});
            p1.h[0] = __float22bfloat162_rn(float2{v1[0], v1[1]});
            p1.h[1] = __float22bfloat162_rn(float2{v1[2], v1[3]});
            p2.h[0] = __float22bfloat162_rn(float2{v2[0], v2[1]});
            p2.h[1] = __float22bfloat162_rn(float2{v2[2], v2[3]});
            p3.h[0] = __float22bfloat162_rn(float2{v3[0], v3[1]});
            p3.h[1] = __float22bfloat162_rn(float2{v3[2], v3[3]});
            *reinterpret_cast<uint2*>(rb + (((0 * 32 + cb) ^ (row & 7)) << 4)) = p0.u;
            *reinterpret_cast<uint2*>(rb + (((1 * 32 + cb) ^ (row & 7)) << 4)) = p1.u;
            *reinterpret_cast<uint2*>(rb + (((2 * 32 + cb) ^ (row & 7)) << 4)) = p2.u;
            *reinterpret_cast<uint2*>(rb + (((3 * 32 + cb) ^ (row & 7)) << 4)) = p3.u;
        }
    }
    __syncthreads();

    // ================= PHASE 2: k-loop =================
    const int rt = w & 1, fh = w >> 1;          // wave -> (row-tile, f-half)
    const int arow = rt * 16 + lrow;
    const char* abase = Alds + arow * 2048;
    const int axor = arow & 7;
    int bo[4];
#pragma unroll
    for (int ft = 0; ft < 4; ++ft) {
        const int f = fh * 64 + ft * 16 + lrow;
        bo[ft] = ((f * 4 + kg) ^ ((f >> 1) & 3)) << 4;
    }
    const char* bSrc = (const char*)Bpack + (size_t)split * (KSTEPS * 8192) + t * 16;

    f32x4 acc[4];
#pragma unroll
    for (int i = 0; i < 4; ++i) acc[i] = f32x4{0.f, 0.f, 0.f, 0.f};

#define STAGE_B(KS, P) do {                                                                        \
        __builtin_amdgcn_global_load_lds(AS1(bSrc + (size_t)(KS) * 8192),        AS3(&Blds[P][0] + t * 16), 16, 0, 0);        \
        __builtin_amdgcn_global_load_lds(AS1(bSrc + (size_t)(KS) * 8192 + 4096), AS3(&Blds[P][0] + 4096 + t * 16), 16, 0, 0); \
    } while (0)

    __builtin_amdgcn_sched_barrier(0);
    STAGE_B(0, 0);
    __builtin_amdgcn_sched_barrier(0);

    for (int ks = 0; ks < KSTEPS; ++ks) {
        const int cur = ks & 1;
        if (ks + 1 < KSTEPS) {
            STAGE_B(ks + 1, cur ^ 1);
            __builtin_amdgcn_sched_barrier(0);
            asm volatile("s_waitcnt vmcnt(2)" ::: "memory");   // tile ks landed
        } else {
            asm volatile("s_waitcnt vmcnt(0)" ::: "memory");
        }
        __builtin_amdgcn_s_barrier();
        __builtin_amdgcn_sched_barrier(0);

        const short8 av = *reinterpret_cast<const short8*>(abase + (((ks * 4 + kg) ^ axor) << 4));
        const char* B = &Blds[cur][0];
        short8 bv[4];
#pragma unroll
        for (int ft = 0; ft < 4; ++ft)
            bv[ft] = *reinterpret_cast<const short8*>(B + bo[ft]);

        asm volatile("s_waitcnt lgkmcnt(0)" ::: "memory");
        __builtin_amdgcn_sched_barrier(0);
        __builtin_amdgcn_s_setprio(1);
#pragma unroll
        for (int ft = 0; ft < 4; ++ft)
            acc[ft] = __builtin_amdgcn_mfma_f32_16x16x32_bf16(av, bv[ft], acc[ft], 0, 0, 0);
        __builtin_amdgcn_s_setprio(0);
        __builtin_amdgcn_sched_barrier(0);
        if (ks + 1 < KSTEPS) {
            __builtin_amdgcn_s_barrier();        // B reads done before next stage overwrites
            __builtin_amdgcn_sched_barrier(0);
        }
    }
#undef STAGE_B

    // epilogue: C row = n0 + rt*16 + kg*4 + rr, col = fh*64 + ft*16 + lrow
    const int crow = n0 + rt * 16 + (kg << 2);
    float* pb = partial + ((size_t)split * 1024 + crow) * FD + fh * 64 + lrow;
#pragma unroll
    for (int ft = 0; ft < 4; ++ft)
#pragma unroll
        for (int rr = 0; rr < 4; ++rr)
            __builtin_nontemporal_store(acc[ft][rr], pb + (size_t)rr * FD + ft * 16);
}

// Stage 4: reduce split-K partials (nt loads), cosine sim
__global__ __launch_bounds__(128) void k_sims(const float* __restrict__ partial,
                                              const float* __restrict__ rep0,
                                              float* __restrict__ sims)
{
    const int n = blockIdx.x;
    const int f = threadIdx.x;
    float rsum = 0.f;
    for (int s = 0; s < NSPLIT; ++s)
        rsum += __builtin_nontemporal_load(partial + ((size_t)s * 1024 + n) * FD + f);
    const float r0 = rep0[f];
    __shared__ float red0[128], red1[128], red2[128];
    red0[f] = rsum * r0;
    red1[f] = rsum * rsum;
    red2[f] = r0 * r0;
    __syncthreads();
    for (int o = 64; o > 0; o >>= 1) {
        if (f < o) {
            red0[f] += red0[f + o];
            red1[f] += red1[f + o];
            red2[f] += red2[f + o];
        }
        __syncthreads();
    }
    if (f == 0) {
        const float nr = fmaxf(sqrtf(red1[0]), 1e-8f);
        const float nz = fmaxf(sqrtf(red2[0]), 1e-8f);
        sims[n] = red0[0] / (nr * nz);
    }
}

// Stage 5a: per-pixel weighted sums S0,S1,S2 over an n-chunk, float4 pixels
__global__ __launch_bounds__(256) void k_colsums(const float* __restrict__ masks,
                                                 const float* __restrict__ sims,
                                                 float* __restrict__ Spart)
{
    __shared__ float s1v[NPB], s2v[NPB];
    const int t = threadIdx.x;
    const int split = blockIdx.y;
    if (t < NPB) {
        const float s = sims[split * NPB + t];
        s1v[t] = s;
        s2v[t] = s * s;
    }
    __syncthreads();
    const int pix = (blockIdx.x * 256 + t) * 4;
    const float* mp = masks + (size_t)split * NPB * HWN + pix;
    f32x4 s0 = {0.f,0.f,0.f,0.f}, s1 = s0, s2 = s0;
#pragma unroll 5
    for (int i = 0; i < NPB; ++i) {
        const f32x4 m = *reinterpret_cast<const f32x4*>(mp + (size_t)i * HWN);
        const float a = s1v[i], b = s2v[i];
        s0 += m;
#pragma unroll
        for (int e = 0; e < 4; ++e) {
            s1[e] = fmaf(m[e], a, s1[e]);
            s2[e] = fmaf(m[e], b, s2[e]);
        }
    }
    float* sp = Spart + (size_t)split * 3 * HWN + pix;
    __builtin_nontemporal_store(s0, reinterpret_cast<f32x4*>(sp));
    __builtin_nontemporal_store(s1, reinterpret_cast<f32x4*>(sp + HWN));
    __builtin_nontemporal_store(s2, reinterpret_cast<f32x4*>(sp + 2 * HWN));
}

// Stage 5b: combine splits, closed-form imp/unc/sow
__global__ __launch_bounds__(256) void k_final(const float* __restrict__ Spart,
                                               float* __restrict__ out)
{
    const int pix = (blockIdx.x * 256 + threadIdx.x) * 4;
    f32x4 s0 = {0.f,0.f,0.f,0.f}, s1 = s0, s2 = s0;
#pragma unroll 4
    for (int sp = 0; sp < NSCAN; ++sp) {
        const float* p = Spart + (size_t)sp * 3 * HWN + pix;
        s0 += __builtin_nontemporal_load(reinterpret_cast<const f32x4*>(p));
        s1 += __builtin_nontemporal_load(reinterpret_cast<const f32x4*>(p + HWN));
        s2 += __builtin_nontemporal_load(reinterpret_cast<const f32x4*>(p + 2 * HWN));
    }
    f32x4 imp, unc, sow;
#pragma unroll
    for (int e = 0; e < 4; ++e) {
        sow[e] = 1e-10f + s0[e];
        imp[e] = s1[e] / sow[e];
        unc[e] = fmaf(-imp[e], s1[e], s2[e]);   // S2 - S1^2/sow
    }
    *reinterpret_cast<f32x4*>(out + pix) = imp;
    *reinterpret_cast<f32x4*>(out + HWN + pix) = unc;
    *reinterpret_cast<f32x4*>(out + 2 * HWN + pix) = sow;
}

extern "C" void kernel_launch(void* const* d_in, const int* in_sizes, int n_in,
                              void* d_out, int out_size, void* d_ws, size_t ws_size,
                              hipStream_t stream) {
    const float* img   = (const float*)d_in[0];
    const float* masks = (const float*)d_in[1];
    const float* Wt    = (const float*)d_in[2];
    float* out = (float*)d_out;

    char* ws = (char*)d_ws;
    unsigned short* Bpack = (unsigned short*)ws;                 // 12,845,056 B
    float* partial  = (float*)(ws + 12845056);                   // 25,690,112 B
    float* rep0part = partial;                                   // alias: consumed before gemm writes
    float* rep0     = (float*)(ws + 38535168);                   // 512 B
    float* sims     = (float*)(ws + 38535680);                   // 4,000 B
    float* Spart    = (float*)ws;                                // alias Bpack (12,042,240 B)

    hipLaunchKernelGGL(k_encode,  dim3(784), dim3(256), 0, stream, img, Wt, Bpack, rep0part);
    hipLaunchKernelGGL(k_rep0red, dim3(128), dim3(256), 0, stream, rep0part, rep0);
    hipLaunchKernelGGL(k_gemm,    dim3(1568), dim3(256), 0, stream, masks, Bpack, partial);
    hipLaunchKernelGGL(k_sims,    dim3(NM), dim3(128), 0, stream, partial, rep0, sims);
    hipLaunchKernelGGL(k_colsums, dim3(49, NSCAN), dim3(256), 0, stream, masks, sims, Spart);
    hipLaunchKernelGGL(k_final,   dim3(49), dim3(256), 0, stream, Spart, out);
}

// Round 11
// 134.462 us; speedup vs baseline: 1.1665x; 1.1665x over previous
//
#include <hip/hip_runtime.h>
#include <hip/hip_bf16.h>
#include <stdint.h>

#define HWN 50176   // 224*224
#define NM  1000
#define FD  128
#define NSPLIT 49   // 1024-wide k-windows
#define NSCAN 20
#define NPB 50      // 1000 / 20

typedef __attribute__((ext_vector_type(8))) short short8;
typedef __attribute__((ext_vector_type(4))) float f32x4;

__device__ __forceinline__ unsigned short f2bf(float x) {
    union { float f; unsigned u; } v; v.f = x;
    unsigned r = v.u + 0x7FFFu + ((v.u >> 16) & 1u);
    return (unsigned short)(r >> 16);
}

#define AS1(p) ((const __attribute__((address_space(1))) unsigned int*)(p))
#define AS3(p) ((__attribute__((address_space(3))) unsigned int*)(p))

// Stage 1: A[hw,f] = sum_c img*W, packed bf16 k-tiles (GEMM B operand).
// Tile kt (8192B): 16B chunk (f, j) at slot (f*4+j)^((f>>1)&3).
__global__ __launch_bounds__(256) void k_encode(const float* __restrict__ img,
                                                const float* __restrict__ Wt,
                                                unsigned short* __restrict__ Bpack,
                                                float* __restrict__ rep0part)
{
    const int t = threadIdx.x;
    const int f = t & 127;
    const int kt = blockIdx.x * 2 + (t >> 7);
    const int hw0 = kt * 32;
    float vals[32];
    float rsum = 0.f;
#pragma unroll
    for (int e = 0; e < 32; ++e) {
        const int hw = hw0 + e;
        float a = img[hw] * __builtin_nontemporal_load(Wt + (size_t)hw * FD + f);
        a = fmaf(img[HWN + hw],     __builtin_nontemporal_load(Wt + (size_t)(HWN + hw) * FD + f), a);
        a = fmaf(img[2 * HWN + hw], __builtin_nontemporal_load(Wt + (size_t)(2 * HWN + hw) * FD + f), a);
        vals[e] = a;
        rsum += a;
    }
    char* tile = (char*)Bpack + (size_t)kt * 8192;
#pragma unroll
    for (int j = 0; j < 4; ++j) {
        short8 pk;
#pragma unroll
        for (int e = 0; e < 8; ++e) pk[e] = (short)f2bf(vals[j * 8 + e]);
        const int slot = (f * 4 + j) ^ ((f >> 1) & 3);
        *reinterpret_cast<short8*>(tile + (slot << 4)) = pk;
    }
    __shared__ float red[256];
    red[t] = rsum;
    __syncthreads();
    if (t < 128) rep0part[(size_t)blockIdx.x * 128 + f] = red[t] + red[t + 128];
}

// Stage 2: rep0[f] = sum of 784 partials
__global__ __launch_bounds__(256) void k_rep0red(const float* __restrict__ rep0part,
                                                 float* __restrict__ rep0)
{
    const int f = blockIdx.x;
    float s = 0.f;
    for (int b = threadIdx.x; b < 784; b += 256) s += rep0part[(size_t)b * 128 + f];
    __shared__ float red[256];
    red[threadIdx.x] = s;
    __syncthreads();
    for (int o = 128; o > 0; o >>= 1) {
        if (threadIdx.x < o) red[threadIdx.x] += red[threadIdx.x + o];
        __syncthreads();
    }
    if (threadIdx.x == 0) rep0[f] = red[0];
}

// Stage 3: B-stationary barrier-light GEMM.
// Block = (1024k window, 64 rows), grid 49x16=784, 4 waves, 128KB LDS.
// 8 phases (sp 0..3 x mt 0..1): B(sp) 64KB stationary in LDS; A staged via
// gll where each WAVE-INSTRUCTION reads 1KB contiguous of ONE mask row
// (colsums' proven-fast pattern), fp32, XOR-swizzled rows, double-buffered.
// Inner 8-step k-loop: ds_read + cvt + 4 MFMA, ZERO barriers/waitcnts.
// R11 fix: B_STAGE now covers the full 64KB (16 ops x 4KB; R10 wrote only
// 16KB and read 48KB of poison -> NaN).
__global__ __launch_bounds__(256, 1) void k_gemm(const float* __restrict__ masks,
                                                 const unsigned short* __restrict__ Bpack,
                                                 float* __restrict__ partial)
{
    __shared__ __align__(16) char Alds[2][32768];  // 32 rows x 1KB fp32, swizzled
    __shared__ __align__(16) char Blds[65536];     // 8 kt x 8KB (pre-rotated pack)

    const int t = threadIdx.x;
    const int w = t >> 6, lane = t & 63;
    const int lrow = lane & 15, kg = lane >> 4;

    // XCD swizzle: contiguous swz per XCD -> whole windows per XCD (B L2-reuse)
    const int bid = blockIdx.x;
    const int swz = (bid & 7) * 98 + (bid >> 3);
    const int win = swz >> 4, rg = swz & 15;       // window 0..48, rowgroup 0..15

    const int kbase = win * 1024;                  // float offset in each mask row

    // A staging: inst i, wave w -> local row i*4+w; lanes cover that row's 1KB
    // (source XOR-permuted within 128B lines; LDS linear). 8 vmem ops.
#define A_STAGE(SP, MT, BUF) do {                                                         \
        _Pragma("unroll")                                                                 \
        for (int i = 0; i < 8; ++i) {                                                     \
            const int rl = i * 4 + w;                                                     \
            int grow = rg * 64 + (MT) * 32 + rl; if (grow >= NM) grow = NM - 1;           \
            const float* src = masks + (size_t)grow * HWN + kbase + (SP) * 256            \
                               + (((lane * 16) ^ ((rl & 7) << 4)) >> 2);                  \
            __builtin_amdgcn_global_load_lds(AS1(src),                                    \
                AS3(&Alds[BUF][0] + rl * 1024 + lane * 16), 16, 0, 0);                    \
        }                                                                                 \
    } while (0)

    // B staging: 64KB = 16 ops x (256 thr x 16B). 16 vmem ops.
#define B_STAGE(SP) do {                                                                  \
        const char* bsrc = (const char*)Bpack + ((size_t)win * 32 + (SP) * 8) * 8192;     \
        _Pragma("unroll")                                                                 \
        for (int j = 0; j < 16; ++j)                                                      \
            __builtin_amdgcn_global_load_lds(AS1(bsrc + j * 4096 + t * 16),               \
                AS3(&Blds[0] + j * 4096 + t * 16), 16, 0, 0);                             \
    } while (0)

    // fragment geometry
    const int rt = w & 1, fh = w >> 1;
    const int r = rt * 16 + lrow;                  // A-LDS row 0..31
    const int swr = (r & 7) << 4;
    int bo[4];
#pragma unroll
    for (int ft = 0; ft < 4; ++ft) {
        const int f = fh * 64 + ft * 16 + lrow;
        bo[ft] = ((f * 4 + kg) ^ ((f >> 1) & 3)) << 4;
    }

    f32x4 acc0[4], acc1[4];
#pragma unroll
    for (int i = 0; i < 4; ++i) { acc0[i] = f32x4{0.f,0.f,0.f,0.f}; acc1[i] = acc0[i]; }

#define KLOOP(BUF, ACC) do {                                                              \
        _Pragma("unroll")                                                                 \
        for (int ks = 0; ks < 8; ++ks) {                                                  \
            const int o = ks * 128 + kg * 32;                                             \
            const f32x4 lo = *reinterpret_cast<const f32x4*>(&Alds[BUF][0] + r * 1024 + (o ^ swr));        \
            const f32x4 hi = *reinterpret_cast<const f32x4*>(&Alds[BUF][0] + r * 1024 + ((o + 16) ^ swr)); \
            union { short8 s; __hip_bfloat162 h[4]; } apk;                                \
            apk.h[0] = __float22bfloat162_rn(float2{lo[0], lo[1]});                       \
            apk.h[1] = __float22bfloat162_rn(float2{lo[2], lo[3]});                       \
            apk.h[2] = __float22bfloat162_rn(float2{hi[0], hi[1]});                       \
            apk.h[3] = __float22bfloat162_rn(float2{hi[2], hi[3]});                       \
            _Pragma("unroll")                                                             \
            for (int ft = 0; ft < 4; ++ft) {                                              \
                const short8 bv = *reinterpret_cast<const short8*>(&Blds[0] + ks * 8192 + bo[ft]); \
                ACC[ft] = __builtin_amdgcn_mfma_f32_16x16x32_bf16(apk.s, bv, ACC[ft], 0, 0, 0);    \
            }                                                                             \
        }                                                                                 \
    } while (0)

    // prologue: A(p0)=8, B(sp0)=16, A(p1)=8 in flight (32); wait all but 8
    A_STAGE(0, 0, 0);
    B_STAGE(0);
    A_STAGE(0, 1, 1);
    asm volatile("s_waitcnt vmcnt(8)" ::: "memory");   // A(p0)+B landed; A(p1) in flight
    __builtin_amdgcn_s_barrier();
    __builtin_amdgcn_sched_barrier(0);

    // 8 phases, fully unrolled so acc indexing is static
#pragma unroll
    for (int p = 0; p < 8; ++p) {
        const int mt = p & 1, buf = p & 1;
        if (mt == 0) KLOOP(buf, acc0); else KLOOP(buf, acc1);
        if (p == 7) break;
        __builtin_amdgcn_s_barrier();            // phase p done by all waves
        __builtin_amdgcn_sched_barrier(0);
        const int pn = p + 1;
        if ((pn & 1) == 0) B_STAGE(pn >> 1);     // new sp: reload B (16 ops, exposed)
        if (pn + 1 <= 7) {
            const int spn = (pn + 1) >> 1, mtn = (pn + 1) & 1;
            if (spn == 1 && mtn == 0) A_STAGE(1, 0, 0);
            if (spn == 1 && mtn == 1) A_STAGE(1, 1, 1);
            if (spn == 2 && mtn == 0) A_STAGE(2, 0, 0);
            if (spn == 2 && mtn == 1) A_STAGE(2, 1, 1);
            if (spn == 3 && mtn == 0) A_STAGE(3, 0, 0);
            if (spn == 3 && mtn == 1) A_STAGE(3, 1, 1);
            asm volatile("s_waitcnt vmcnt(8)" ::: "memory");   // A(pn)+B landed; A(pn+1) in flight
        } else {
            asm volatile("s_waitcnt vmcnt(0)" ::: "memory");   // tail: A(7) landed
        }
        __builtin_amdgcn_s_barrier();
        __builtin_amdgcn_sched_barrier(0);
    }
#undef KLOOP
#undef A_STAGE
#undef B_STAGE

    // epilogue: row = rg*64 + mt*32 + rt*16 + kg*4 + rr, col = fh*64 + ft*16 + lrow
    const int crow = rg * 64 + rt * 16 + (kg << 2);
    float* pb0 = partial + ((size_t)win * 1024 + crow) * FD + fh * 64 + lrow;
    float* pb1 = pb0 + 32 * FD;
#pragma unroll
    for (int ft = 0; ft < 4; ++ft)
#pragma unroll
        for (int rr = 0; rr < 4; ++rr) {
            __builtin_nontemporal_store(acc0[ft][rr], pb0 + (size_t)rr * FD + ft * 16);
            __builtin_nontemporal_store(acc1[ft][rr], pb1 + (size_t)rr * FD + ft * 16);
        }
}

// Stage 4: reduce split-K partials (nt loads), cosine sim
__global__ __launch_bounds__(128) void k_sims(const float* __restrict__ partial,
                                              const float* __restrict__ rep0,
                                              float* __restrict__ sims)
{
    const int n = blockIdx.x;
    const int f = threadIdx.x;
    float rsum = 0.f;
    for (int s = 0; s < NSPLIT; ++s)
        rsum += __builtin_nontemporal_load(partial + ((size_t)s * 1024 + n) * FD + f);
    const float r0 = rep0[f];
    __shared__ float red0[128], red1[128], red2[128];
    red0[f] = rsum * r0;
    red1[f] = rsum * rsum;
    red2[f] = r0 * r0;
    __syncthreads();
    for (int o = 64; o > 0; o >>= 1) {
        if (f < o) {
            red0[f] += red0[f + o];
            red1[f] += red1[f + o];
            red2[f] += red2[f + o];
        }
        __syncthreads();
    }
    if (f == 0) {
        const float nr = fmaxf(sqrtf(red1[0]), 1e-8f);
        const float nz = fmaxf(sqrtf(red2[0]), 1e-8f);
        sims[n] = red0[0] / (nr * nz);
    }
}

// Stage 5a: per-pixel weighted sums S0,S1,S2 over an n-chunk, float4 pixels
__global__ __launch_bounds__(256) void k_colsums(const float* __restrict__ masks,
                                                 const float* __restrict__ sims,
                                                 float* __restrict__ Spart)
{
    __shared__ float s1v[NPB], s2v[NPB];
    const int t = threadIdx.x;
    const int split = blockIdx.y;
    if (t < NPB) {
        const float s = sims[split * NPB + t];
        s1v[t] = s;
        s2v[t] = s * s;
    }
    __syncthreads();
    const int pix = (blockIdx.x * 256 + t) * 4;
    const float* mp = masks + (size_t)split * NPB * HWN + pix;
    f32x4 s0 = {0.f,0.f,0.f,0.f}, s1 = s0, s2 = s0;
#pragma unroll 5
    for (int i = 0; i < NPB; ++i) {
        const f32x4 m = *reinterpret_cast<const f32x4*>(mp + (size_t)i * HWN);
        const float a = s1v[i], b = s2v[i];
        s0 += m;
#pragma unroll
        for (int e = 0; e < 4; ++e) {
            s1[e] = fmaf(m[e], a, s1[e]);
            s2[e] = fmaf(m[e], b, s2[e]);
        }
    }
    float* sp = Spart + (size_t)split * 3 * HWN + pix;
    __builtin_nontemporal_store(s0, reinterpret_cast<f32x4*>(sp));
    __builtin_nontemporal_store(s1, reinterpret_cast<f32x4*>(sp + HWN));
    __builtin_nontemporal_store(s2, reinterpret_cast<f32x4*>(sp + 2 * HWN));
}

// Stage 5b: combine splits, closed-form imp/unc/sow
__global__ __launch_bounds__(256) void k_final(const float* __restrict__ Spart,
                                               float* __restrict__ out)
{
    const int pix = (blockIdx.x * 256 + threadIdx.x) * 4;
    f32x4 s0 = {0.f,0.f,0.f,0.f}, s1 = s0, s2 = s0;
#pragma unroll 4
    for (int sp = 0; sp < NSCAN; ++sp) {
        const float* p = Spart + (size_t)sp * 3 * HWN + pix;
        s0 += __builtin_nontemporal_load(reinterpret_cast<const f32x4*>(p));
        s1 += __builtin_nontemporal_load(reinterpret_cast<const f32x4*>(p + HWN));
        s2 += __builtin_nontemporal_load(reinterpret_cast<const f32x4*>(p + 2 * HWN));
    }
    f32x4 imp, unc, sow;
#pragma unroll
    for (int e = 0; e < 4; ++e) {
        sow[e] = 1e-10f + s0[e];
        imp[e] = s1[e] / sow[e];
        unc[e] = fmaf(-imp[e], s1[e], s2[e]);   // S2 - S1^2/sow
    }
    *reinterpret_cast<f32x4*>(out + pix) = imp;
    *reinterpret_cast<f32x4*>(out + HWN + pix) = unc;
    *reinterpret_cast<f32x4*>(out + 2 * HWN + pix) = sow;
}

extern "C" void kernel_launch(void* const* d_in, const int* in_sizes, int n_in,
                              void* d_out, int out_size, void* d_ws, size_t ws_size,
                              hipStream_t stream) {
    const float* img   = (const float*)d_in[0];
    const float* masks = (const float*)d_in[1];
    const float* Wt    = (const float*)d_in[2];
    float* out = (float*)d_out;

    char* ws = (char*)d_ws;
    unsigned short* Bpack = (unsigned short*)ws;                 // 12,845,056 B
    float* partial  = (float*)(ws + 12845056);                   // 25,690,112 B
    float* rep0part = partial;                                   // alias: consumed before gemm writes
    float* rep0     = (float*)(ws + 38535168);                   // 512 B
    float* sims     = (float*)(ws + 38535680);                   // 4,000 B
    float* Spart    = (float*)ws;                                // alias Bpack (12,042,240 B)

    hipLaunchKernelGGL(k_encode,  dim3(784), dim3(256), 0, stream, img, Wt, Bpack, rep0part);
    hipLaunchKernelGGL(k_rep0red, dim3(128), dim3(256), 0, stream, rep0part, rep0);
    hipLaunchKernelGGL(k_gemm,    dim3(784), dim3(256), 0, stream, masks, Bpack, partial);
    hipLaunchKernelGGL(k_sims,    dim3(NM), dim3(128), 0, stream, partial, rep0, sims);
    hipLaunchKernelGGL(k_colsums, dim3(49, NSCAN), dim3(256), 0, stream, masks, sims, Spart);
    hipLaunchKernelGGL(k_final,   dim3(49), dim3(256), 0, stream, Spart, out);
}

// Round 12
// 134.316 us; speedup vs baseline: 1.1678x; 1.0011x over previous
//
#include <hip/hip_runtime.h>
#include <hip/hip_bf16.h>
#include <stdint.h>

#define HWN 50176   // 224*224
#define NM  1000
#define FD  128
#define NSPLIT 49   // 1024-wide k-windows
#define KSTEPS 32
#define NRG 63      // rowgroups of 16 (last clamps)
#define NSCAN 20
#define NPB 50      // 1000 / 20

typedef __attribute__((ext_vector_type(8))) short short8;
typedef __attribute__((ext_vector_type(4))) float f32x4;

__device__ __forceinline__ unsigned short f2bf(float x) {
    union { float f; unsigned u; } v; v.f = x;
    unsigned r = v.u + 0x7FFFu + ((v.u >> 16) & 1u);
    return (unsigned short)(r >> 16);
}

#define AS1(p) ((const __attribute__((address_space(1))) unsigned int*)(p))
#define AS3(p) ((__attribute__((address_space(3))) unsigned int*)(p))

// Stage 1: A[hw,f] = sum_c img*W, packed bf16 k-tiles (GEMM B operand).
// Tile kt (8192B): 16B chunk (f, j) at slot (f*4+j)^((f>>1)&3).
__global__ __launch_bounds__(256) void k_encode(const float* __restrict__ img,
                                                const float* __restrict__ Wt,
                                                unsigned short* __restrict__ Bpack,
                                                float* __restrict__ rep0part)
{
    const int t = threadIdx.x;
    const int f = t & 127;
    const int kt = blockIdx.x * 2 + (t >> 7);
    const int hw0 = kt * 32;
    float vals[32];
    float rsum = 0.f;
#pragma unroll
    for (int e = 0; e < 32; ++e) {
        const int hw = hw0 + e;
        float a = img[hw] * __builtin_nontemporal_load(Wt + (size_t)hw * FD + f);
        a = fmaf(img[HWN + hw],     __builtin_nontemporal_load(Wt + (size_t)(HWN + hw) * FD + f), a);
        a = fmaf(img[2 * HWN + hw], __builtin_nontemporal_load(Wt + (size_t)(2 * HWN + hw) * FD + f), a);
        vals[e] = a;
        rsum += a;
    }
    char* tile = (char*)Bpack + (size_t)kt * 8192;
#pragma unroll
    for (int j = 0; j < 4; ++j) {
        short8 pk;
#pragma unroll
        for (int e = 0; e < 8; ++e) pk[e] = (short)f2bf(vals[j * 8 + e]);
        const int slot = (f * 4 + j) ^ ((f >> 1) & 3);
        *reinterpret_cast<short8*>(tile + (slot << 4)) = pk;
    }
    __shared__ float red[256];
    red[t] = rsum;
    __syncthreads();
    if (t < 128) rep0part[(size_t)blockIdx.x * 128 + f] = red[t] + red[t + 128];
}

// Stage 2: rep0[f] = sum of 784 partials
__global__ __launch_bounds__(256) void k_rep0red(const float* __restrict__ rep0part,
                                                 float* __restrict__ rep0)
{
    const int f = blockIdx.x;
    float s = 0.f;
    for (int b = threadIdx.x; b < 784; b += 256) s += rep0part[(size_t)b * 128 + f];
    __shared__ float red[256];
    red[threadIdx.x] = s;
    __syncthreads();
    for (int o = 128; o > 0; o >>= 1) {
        if (threadIdx.x < o) red[threadIdx.x] += red[threadIdx.x + o];
        __syncthreads();
    }
    if (threadIdx.x == 0) rep0[f] = red[0];
}

// Stage 3: BARRIER-FREE 1-wave GEMM. Block = 1 wave = 16 rows x 128 f x 1024 k.
// B staged into wave-private LDS via global_load_lds (vmcnt alone orders
// gll->ds_read within a wave: NO s_barrier in the whole kernel). A global->reg,
// parity-named. 10 vmem ops/step, steady-state s_waitcnt vmcnt(10).
// Grid 63x49=3087 one-wave blocks; 16KB LDS -> ~10 independent waves/CU with
// staggered prefetch chains (vs prior lockstep barrier blocks).
__global__ __launch_bounds__(64, 2) void k_gemm(const float* __restrict__ masks,
                                                const unsigned short* __restrict__ Bpack,
                                                float* __restrict__ partial)
{
    __shared__ __align__(16) char Blds[2][8192];

    const int lane = threadIdx.x & 63;
    const int lrow = lane & 15, kg = lane >> 4;

    // XCD-bijective swizzle: 3087 = 7*386 + 385; xcd<7 gets 386 consecutive.
    const int bid = blockIdx.x;
    const int xcd = bid & 7, idx = bid >> 3;
    const int swz = (xcd < 7 ? xcd * 386 : 2702) + idx;
    const int split = swz / NRG, rg = swz - split * NRG;
    const int n0 = rg * 16;

    int row = n0 + lrow;
    if (row >= NM) row = NM - 1;                   // dup rows never read back
    const float* aSrc = masks + (size_t)row * HWN + split * 1024 + kg * 8;
    const char*  bSrc = (const char*)Bpack + (size_t)split * (KSTEPS * 8192) + lane * 16;

    int bo[8];
#pragma unroll
    for (int ft = 0; ft < 8; ++ft) {
        const int f = ft * 16 + lrow;
        bo[ft] = ((f * 4 + kg) ^ ((f >> 1) & 3)) << 4;
    }

    f32x4 acc[8];
#pragma unroll
    for (int i = 0; i < 8; ++i) acc[i] = f32x4{0.f, 0.f, 0.f, 0.f};

    f32x4 aE0, aE1, aO0, aO1;   // parity-named A regs (static indexing)

    // 10 vmem ops: 8 B-gll (1KB each) + 2 A dwordx4 loads
#define STAGE(KS, P, AR0, AR1) do {                                                        \
        const char* bs_ = bSrc + (size_t)(KS) * 8192;                                      \
        _Pragma("unroll")                                                                  \
        for (int j = 0; j < 8; ++j)                                                        \
            __builtin_amdgcn_global_load_lds(AS1(bs_ + j * 1024),                          \
                AS3(&Blds[P][0] + j * 1024 + lane * 16), 16, 0, 0);                        \
        AR0 = *reinterpret_cast<const f32x4*>(aSrc + (KS) * 32);                           \
        AR1 = *reinterpret_cast<const f32x4*>(aSrc + (KS) * 32 + 4);                       \
    } while (0)

#define COMPUTE(P, A0, A1) do {                                                            \
        short8 bfv[8];                                                                     \
        _Pragma("unroll")                                                                  \
        for (int ft = 0; ft < 8; ++ft)                                                     \
            bfv[ft] = *reinterpret_cast<const short8*>(&Blds[P][0] + bo[ft]);              \
        union { short8 s; __hip_bfloat162 h[4]; } apk;                                     \
        apk.h[0] = __float22bfloat162_rn(float2{A0[0], A0[1]});                            \
        apk.h[1] = __float22bfloat162_rn(float2{A0[2], A0[3]});                            \
        apk.h[2] = __float22bfloat162_rn(float2{A1[0], A1[1]});                            \
        apk.h[3] = __float22bfloat162_rn(float2{A1[2], A1[3]});                            \
        __builtin_amdgcn_s_setprio(1);                                                     \
        _Pragma("unroll")                                                                  \
        for (int ft = 0; ft < 8; ++ft)                                                     \
            acc[ft] = __builtin_amdgcn_mfma_f32_16x16x32_bf16(apk.s, bfv[ft], acc[ft], 0, 0, 0); \
        __builtin_amdgcn_s_setprio(0);                                                     \
    } while (0)

    STAGE(0, 0, aE0, aE1);
#pragma unroll 1
    for (int ks2 = 0; ks2 < KSTEPS / 2; ++ks2) {
        const int ks = 2 * ks2;
        // even step: compute buf0/aE while staging ks+1 into buf1/aO
        STAGE(ks + 1, 1, aO0, aO1);
        asm volatile("s_waitcnt vmcnt(10)" ::: "memory");   // step ks landed
        __builtin_amdgcn_sched_barrier(0);
        COMPUTE(0, aE0, aE1);
        // odd step: compute buf1/aO while staging ks+2 into buf0/aE
        if (ks + 2 < KSTEPS) {
            STAGE(ks + 2, 0, aE0, aE1);
            asm volatile("s_waitcnt vmcnt(10)" ::: "memory");   // step ks+1 landed
        } else {
            asm volatile("s_waitcnt vmcnt(0)" ::: "memory");    // tail
        }
        __builtin_amdgcn_sched_barrier(0);
        COMPUTE(1, aO0, aO1);
    }
#undef STAGE
#undef COMPUTE

    // epilogue: C row = n0 + kg*4 + rr, col = ft*16 + lrow
    const int crow = n0 + (kg << 2);
    float* pb = partial + ((size_t)split * 1024 + crow) * FD + lrow;
#pragma unroll
    for (int ft = 0; ft < 8; ++ft)
#pragma unroll
        for (int rr = 0; rr < 4; ++rr)
            __builtin_nontemporal_store(acc[ft][rr], pb + (size_t)rr * FD + ft * 16);
}

// Stage 4: reduce split-K partials (nt loads), cosine sim
__global__ __launch_bounds__(128) void k_sims(const float* __restrict__ partial,
                                              const float* __restrict__ rep0,
                                              float* __restrict__ sims)
{
    const int n = blockIdx.x;
    const int f = threadIdx.x;
    float rsum = 0.f;
    for (int s = 0; s < NSPLIT; ++s)
        rsum += __builtin_nontemporal_load(partial + ((size_t)s * 1024 + n) * FD + f);
    const float r0 = rep0[f];
    __shared__ float red0[128], red1[128], red2[128];
    red0[f] = rsum * r0;
    red1[f] = rsum * rsum;
    red2[f] = r0 * r0;
    __syncthreads();
    for (int o = 64; o > 0; o >>= 1) {
        if (f < o) {
            red0[f] += red0[f + o];
            red1[f] += red1[f + o];
            red2[f] += red2[f + o];
        }
        __syncthreads();
    }
    if (f == 0) {
        const float nr = fmaxf(sqrtf(red1[0]), 1e-8f);
        const float nz = fmaxf(sqrtf(red2[0]), 1e-8f);
        sims[n] = red0[0] / (nr * nz);
    }
}

// Stage 5a: per-pixel weighted sums S0,S1,S2 over an n-chunk, float4 pixels
__global__ __launch_bounds__(256) void k_colsums(const float* __restrict__ masks,
                                                 const float* __restrict__ sims,
                                                 float* __restrict__ Spart)
{
    __shared__ float s1v[NPB], s2v[NPB];
    const int t = threadIdx.x;
    const int split = blockIdx.y;
    if (t < NPB) {
        const float s = sims[split * NPB + t];
        s1v[t] = s;
        s2v[t] = s * s;
    }
    __syncthreads();
    const int pix = (blockIdx.x * 256 + t) * 4;
    const float* mp = masks + (size_t)split * NPB * HWN + pix;
    f32x4 s0 = {0.f,0.f,0.f,0.f}, s1 = s0, s2 = s0;
#pragma unroll 5
    for (int i = 0; i < NPB; ++i) {
        const f32x4 m = *reinterpret_cast<const f32x4*>(mp + (size_t)i * HWN);
        const float a = s1v[i], b = s2v[i];
        s0 += m;
#pragma unroll
        for (int e = 0; e < 4; ++e) {
            s1[e] = fmaf(m[e], a, s1[e]);
            s2[e] = fmaf(m[e], b, s2[e]);
        }
    }
    float* sp = Spart + (size_t)split * 3 * HWN + pix;
    __builtin_nontemporal_store(s0, reinterpret_cast<f32x4*>(sp));
    __builtin_nontemporal_store(s1, reinterpret_cast<f32x4*>(sp + HWN));
    __builtin_nontemporal_store(s2, reinterpret_cast<f32x4*>(sp + 2 * HWN));
}

// Stage 5b: combine splits, closed-form imp/unc/sow
__global__ __launch_bounds__(256) void k_final(const float* __restrict__ Spart,
                                               float* __restrict__ out)
{
    const int pix = (blockIdx.x * 256 + threadIdx.x) * 4;
    f32x4 s0 = {0.f,0.f,0.f,0.f}, s1 = s0, s2 = s0;
#pragma unroll 4
    for (int sp = 0; sp < NSCAN; ++sp) {
        const float* p = Spart + (size_t)sp * 3 * HWN + pix;
        s0 += __builtin_nontemporal_load(reinterpret_cast<const f32x4*>(p));
        s1 += __builtin_nontemporal_load(reinterpret_cast<const f32x4*>(p + HWN));
        s2 += __builtin_nontemporal_load(reinterpret_cast<const f32x4*>(p + 2 * HWN));
    }
    f32x4 imp, unc, sow;
#pragma unroll
    for (int e = 0; e < 4; ++e) {
        sow[e] = 1e-10f + s0[e];
        imp[e] = s1[e] / sow[e];
        unc[e] = fmaf(-imp[e], s1[e], s2[e]);   // S2 - S1^2/sow
    }
    *reinterpret_cast<f32x4*>(out + pix) = imp;
    *reinterpret_cast<f32x4*>(out + HWN + pix) = unc;
    *reinterpret_cast<f32x4*>(out + 2 * HWN + pix) = sow;
}

extern "C" void kernel_launch(void* const* d_in, const int* in_sizes, int n_in,
                              void* d_out, int out_size, void* d_ws, size_t ws_size,
                              hipStream_t stream) {
    const float* img   = (const float*)d_in[0];
    const float* masks = (const float*)d_in[1];
    const float* Wt    = (const float*)d_in[2];
    float* out = (float*)d_out;

    char* ws = (char*)d_ws;
    unsigned short* Bpack = (unsigned short*)ws;                 // 12,845,056 B
    float* partial  = (float*)(ws + 12845056);                   // 25,690,112 B
    float* rep0part = partial;                                   // alias: consumed before gemm writes
    float* rep0     = (float*)(ws + 38535168);                   // 512 B
    float* sims     = (float*)(ws + 38535680);                   // 4,000 B
    float* Spart    = (float*)ws;                                // alias Bpack (12,042,240 B)

    hipLaunchKernelGGL(k_encode,  dim3(784), dim3(256), 0, stream, img, Wt, Bpack, rep0part);
    hipLaunchKernelGGL(k_rep0red, dim3(128), dim3(256), 0, stream, rep0part, rep0);
    hipLaunchKernelGGL(k_gemm,    dim3(3087), dim3(64), 0, stream, masks, Bpack, partial);
    hipLaunchKernelGGL(k_sims,    dim3(NM), dim3(128), 0, stream, partial, rep0, sims);
    hipLaunchKernelGGL(k_colsums, dim3(49, NSCAN), dim3(256), 0, stream, masks, sims, Spart);
    hipLaunchKernelGGL(k_final,   dim3(49), dim3(256), 0, stream, Spart, out);
}